// Round 9
// baseline (131.877 us; speedup 1.0000x reference)
//
#include <hip/hip_runtime.h>
#include <math.h>

// DigitCaps dynamic routing, B=256 R=1152 C=10 OUT=16 IN=8, fp32 in/out.
// Identity: b_ij(t) = dot(u_hat, Vsum), Vsum = sum of previous v iterates ->
// never store b_ij or u_hat; recompute u_hat each iteration from W (f16).
//
// This round: DS-pipe removed from the hot loop. W16 is read straight from
// global/L2 (the 8 same-address batch lanes coalesce inside one instruction,
// so the 8x duplication is free), and the og-lane logit reduction uses DPP
// adds (quad_perm xor1/xor2 + row_half_mirror) instead of __shfl_xor's
// ds_bpermute. Zero LDS reads, zero barriers in the main loop. Grid places
// all blocks of one chunk-quad on one XCD (blockIdx.x % 8) for L2 W-reuse.
// In-block reduce over the 4 waves -> s_part has 32 slices (5.2 MB).
//
// ws: s_part[32][256][160] f32 (5.24 MB) + Vsum[256][160] f32 (0.16 MB)
//     + W16[1280][1280] f16 (3.28 MB) + X16[256][1280][8] f16 (5.24 MB)

typedef _Float16 h2 __attribute__((ext_vector_type(2)));
typedef _Float16 h4 __attribute__((ext_vector_type(4)));

#if __has_builtin(__builtin_amdgcn_fdot2)
#define FDOT2(a, b, c) __builtin_amdgcn_fdot2((a), (b), (c), false)
#else
static __device__ __forceinline__ float FDOT2(h2 a, h2 b, float c) {
    return c + (float)a.x * (float)b.x + (float)a.y * (float)b.y;
}
#endif

#if __has_builtin(__builtin_amdgcn_rcpf)
#define FRCP(x) __builtin_amdgcn_rcpf(x)
#else
#define FRCP(x) (1.0f / (x))
#endif

#define BCH2(u) __builtin_bit_cast(h2, (u))

// cross-lane add via DPP (VALU, not DS). CTRL: 0xB1 = quad_perm(1,0,3,2) = xor1,
// 0x4E = quad_perm(2,3,0,1) = xor2, 0x141 = ROW_HALF_MIRROR = xor7 within 8
// (valid 3rd stage of an 8-lane sum after xor1+xor2).
template<int CTRL>
static __device__ __forceinline__ float dpp_xadd(float x) {
    const int t = __builtin_amdgcn_update_dpp(
        0, __builtin_bit_cast(int, x), CTRL, 0xF, 0xF, true);
    return x + __builtin_bit_cast(float, t);
}

namespace {
constexpr int Bdim = 256;
constexpr int Rdim = 1152;
constexpr int Cdim = 10;
constexpr int Odim = 16;
constexpr int Idim = 8;
constexpr int CO   = 160;

constexpr int Rpad = 1280;  // zero-padded R (padded rows: u=0 -> exact no-op)
constexpr int RPC  = 10;    // rows per chunk
constexpr int NCH  = 128;   // chunks
constexpr int NSP  = 32;    // s_part slices (= NCH / 4 waves per block)
constexpr int WROW = Cdim * Odim * Idim;   // 1280 f16 per W row
constexpr int REDP = 162;   // padded f32 row stride in reduce buffer
}

// f32 -> f16 with zero padding, W and x (once per launch).
__global__ __launch_bounds__(256)
void conv_wx(const float* __restrict__ W, const float* __restrict__ x,
             _Float16* __restrict__ W16, _Float16* __restrict__ X16)
{
    constexpr int NW4 = Rpad * WROW / 4;          // 409600 h4 slots
    constexpr int NX4 = Bdim * Rpad * Idim / 4;   // 655360 h4 slots
    const int i = blockIdx.x * 256 + threadIdx.x;
    if (i < NW4) {
        const int r = i / (WROW / 4);
        h4 o = { (_Float16)0.f, (_Float16)0.f, (_Float16)0.f, (_Float16)0.f };
        if (r < Rdim) {
            const float4 v = reinterpret_cast<const float4*>(W)[i];
            o = { (_Float16)v.x, (_Float16)v.y, (_Float16)v.z, (_Float16)v.w };
        }
        reinterpret_cast<h4*>(W16)[i] = o;
    } else if (i < NW4 + NX4) {
        const int j   = i - NW4;
        const int b   = j / (Rpad * 2);
        const int rem = j - b * (Rpad * 2);
        const int r   = rem >> 1;
        h4 o = { (_Float16)0.f, (_Float16)0.f, (_Float16)0.f, (_Float16)0.f };
        if (r < Rdim) {
            const float4 v = reinterpret_cast<const float4*>(x)
                [((size_t)b * Rdim + r) * 2 + (rem & 1)];
            o = { (_Float16)v.x, (_Float16)v.y, (_Float16)v.z, (_Float16)v.w };
        }
        reinterpret_cast<h4*>(X16)[j] = o;
    }
}

template<bool FIRST>
__global__ __launch_bounds__(256)
void caps_iter(const _Float16* __restrict__ X16, const _Float16* __restrict__ W16,
               const float* __restrict__ Vsum, float* __restrict__ s_part)
{
    __shared__ float red[32 * REDP];   // 20.7 KB (only the final reduce)

    const int tid  = threadIdx.x;
    const int wv   = tid >> 6;
    const int lane = tid & 63;
    const int og   = lane & 7;          // o-group: o = og*2, og*2+1
    const int bl   = lane >> 3;         // batch within group

    const int quad   = blockIdx.x;      // 0..31 -> XCD quad%8 (W L2 affinity)
    const int bgroup = blockIdx.y;      // 0..31
    const int chunk  = quad * 4 + wv;   // 0..127
    const int r0     = chunk * RPC;
    const int b      = bgroup * 8 + bl;

    // v (= Vsum) registers for (b, all c, o = og*2, og*2+1)
    float va[Cdim], vb[Cdim];
    if constexpr (!FIRST) {
#pragma unroll
        for (int c = 0; c < Cdim; ++c) {
            const float2 vv = *reinterpret_cast<const float2*>(
                Vsum + (size_t)b * CO + c * Odim + og * 2);
            va[c] = vv.x; vb[c] = vv.y;
        }
    }

    float s0[Cdim], s1[Cdim];
#pragma unroll
    for (int c = 0; c < Cdim; ++c) { s0[c] = 0.f; s1[c] = 0.f; }

    const _Float16* Wp = W16 + (size_t)r0 * WROW + og * 16;   // this lane's 2 o's
    const _Float16* Xp = X16 + ((size_t)b * Rpad + r0) * Idim;

#pragma unroll 2
    for (int rr = 0; rr < RPC; ++rr) {
        const uint4 xv = *reinterpret_cast<const uint4*>(Xp + rr * Idim);
        const h2 x0 = BCH2(xv.x), x1 = BCH2(xv.y), x2 = BCH2(xv.z), x3 = BCH2(xv.w);

        const _Float16* wr = Wp + (size_t)rr * WROW;
        float u0[Cdim], u1[Cdim];
#pragma unroll
        for (int c = 0; c < Cdim; ++c) {
            const uint4* wp = reinterpret_cast<const uint4*>(wr + c * (Odim * Idim));
            const uint4 w0 = wp[0], w1 = wp[1];   // base + imm offsets (<=2304B)
            float a = FDOT2(BCH2(w0.x), x0, 0.f);
            a = FDOT2(BCH2(w0.y), x1, a);
            a = FDOT2(BCH2(w0.z), x2, a);
            u0[c] = FDOT2(BCH2(w0.w), x3, a);
            float d = FDOT2(BCH2(w1.x), x0, 0.f);
            d = FDOT2(BCH2(w1.y), x1, d);
            d = FDOT2(BCH2(w1.z), x2, d);
            u1[c] = FDOT2(BCH2(w1.w), x3, d);
        }

        if constexpr (FIRST) {
#pragma unroll
            for (int c = 0; c < Cdim; ++c) {
                s0[c] += 0.1f * u0[c];    // softmax of zeros over C=10
                s1[c] += 0.1f * u1[c];
            }
        } else {
            float e[Cdim];
            float sum = 0.f;
#pragma unroll
            for (int c = 0; c < Cdim; ++c) {
                float l = u0[c] * va[c] + u1[c] * vb[c];
                l = dpp_xadd<0xB1>(l);    // xor1 (quad_perm 1,0,3,2)
                l = dpp_xadd<0x4E>(l);    // xor2 (quad_perm 2,3,0,1)
                l = dpp_xadd<0x141>(l);   // row_half_mirror (xor7 within 8)
                e[c] = __expf(l);         // |l| small: f32-safe, no max pass
                sum += e[c];
            }
            const float rinv = FRCP(sum);
#pragma unroll
            for (int c = 0; c < Cdim; ++c) {
                const float cw = e[c] * rinv;
                s0[c] += cw * u0[c];
                s1[c] += cw * u1[c];
            }
        }
    }

    // in-block reduce over the 4 waves' chunks -> one slice per block
    {
        float* myrow = red + (wv * 8 + bl) * REDP + og * 2;
#pragma unroll
        for (int c = 0; c < Cdim; ++c)
            *reinterpret_cast<float2*>(myrow + c * Odim) = make_float2(s0[c], s1[c]);
    }
    __syncthreads();
#pragma unroll
    for (int k = 0; k < 5; ++k) {
        const int j  = k * 256 + tid;        // 0..1279 covers 8 b x 160 co
        const int b2 = j / CO;
        const int co = j - b2 * CO;
        const int o  = b2 * REDP + co;
        const float t = red[o] + red[8 * REDP + o]
                      + red[16 * REDP + o] + red[24 * REDP + o];
        s_part[((size_t)quad * Bdim + bgroup * 8 + b2) * CO + co] = t;
    }
}

// Sum the NSP partials, squash; MODE 0: Vsum = v (it0, replaces memset),
// MODE 1: Vsum += v, MODE 2: out = v.
template<int MODE>
__global__ __launch_bounds__(256)
void caps_reduce(const float* __restrict__ s_part, float* __restrict__ Vsum,
                 float* __restrict__ out)
{
    const int idx = blockIdx.x * 256 + threadIdx.x;   // < 40960 = B*C*O
    float s = 0.f;
#pragma unroll 8
    for (int k = 0; k < NSP; ++k) s += s_part[(size_t)k * (Bdim * CO) + idx];

    float ssq = s * s;
    ssq += __shfl_xor(ssq, 1);
    ssq += __shfl_xor(ssq, 2);
    ssq += __shfl_xor(ssq, 4);
    ssq += __shfl_xor(ssq, 8);

    const float mag = sqrtf(ssq + 1e-8f);
    const float v = ssq / (1.f + ssq) * s / (mag + 1e-8f);

    if constexpr (MODE == 2) out[idx] = v;
    else if constexpr (MODE == 1) Vsum[idx] += v;
    else Vsum[idx] = v;
}

extern "C" void kernel_launch(void* const* d_in, const int* in_sizes, int n_in,
                              void* d_out, int out_size, void* d_ws, size_t ws_size,
                              hipStream_t stream)
{
    const float* x = (const float*)d_in[0];   // [256,1152,8]
    const float* W = (const float*)d_in[1];   // [1152,10,16,8]
    float* out = (float*)d_out;               // [256,10,16]

    float* s_part = (float*)d_ws;                           // 32*256*160 f32
    float* Vsum   = s_part + (size_t)NSP * Bdim * CO;       // 256*160 f32
    _Float16* W16 = (_Float16*)(Vsum + Bdim * CO);          // 1280*1280 f16
    _Float16* X16 = W16 + (size_t)Rpad * WROW;              // 256*1280*8 f16

    // (409600 + 655360) / 256 = 4160 blocks, exact
    conv_wx<<<dim3(4160), dim3(256), 0, stream>>>(W, x, W16, X16);

    const dim3 gi(NSP, Bdim / 8);    // x = chunk-quad (XCD affinity), y = bgroup
    const dim3 bi(256);
    const dim3 gr((Bdim * CO) / 256);
    const dim3 br(256);

    // it 0
    caps_iter<true><<<gi, bi, 0, stream>>>(X16, W16, Vsum, s_part);
    caps_reduce<0><<<gr, br, 0, stream>>>(s_part, Vsum, out);
    // it 1
    caps_iter<false><<<gi, bi, 0, stream>>>(X16, W16, Vsum, s_part);
    caps_reduce<1><<<gr, br, 0, stream>>>(s_part, Vsum, out);
    // it 2 (final -> d_out)
    caps_iter<false><<<gi, bi, 0, stream>>>(X16, W16, Vsum, s_part);
    caps_reduce<2><<<gr, br, 0, stream>>>(s_part, Vsum, out);
}

// Round 10
// 101.332 us; speedup vs baseline: 1.3014x; 1.3014x over previous
//
#include <hip/hip_runtime.h>
#include <math.h>

// DigitCaps dynamic routing, B=256 R=1152 C=10 OUT=16 IN=8, fp32 in/out.
// Identity: b_ij(t) = dot(u_hat, Vsum), Vsum = sum of previous v iterates ->
// never store b_ij or u_hat; recompute u_hat each iteration from W (f16).
//
// Round-10 structure: R7's wave-private LDS W double-buffer (global_load_lds,
// barrier-free, per-wave vmcnt(0)) + T=2 batches/thread (wave = 16 batches ->
// halves W LDS-read instructions) + R9's DPP og-lane reduction (zero DS ops in
// softmax). x transposed to [Rpad][B][8] f16 for coalesced row loads.
// DS-pipe load per CU drops ~4.5x vs R7 -> VALU-bound (~6 us/iter floor).
//
// ws: s_part[32][256][160] f32 (5.24 MB) + Vsum[256][160] f32 (0.16 MB)
//     + W16[1280][1280] f16 (3.28 MB) + X16t[1280][256][8] f16 (5.24 MB)

typedef _Float16 h2 __attribute__((ext_vector_type(2)));
typedef _Float16 h4 __attribute__((ext_vector_type(4)));

#if __has_builtin(__builtin_amdgcn_fdot2)
#define FDOT2(a, b, c) __builtin_amdgcn_fdot2((a), (b), (c), false)
#else
static __device__ __forceinline__ float FDOT2(h2 a, h2 b, float c) {
    return c + (float)a.x * (float)b.x + (float)a.y * (float)b.y;
}
#endif

#if __has_builtin(__builtin_amdgcn_rcpf)
#define FRCP(x) __builtin_amdgcn_rcpf(x)
#else
#define FRCP(x) (1.0f / (x))
#endif

#define BCH2(u) __builtin_bit_cast(h2, (u))

// cross-lane add via DPP (VALU, not DS). 0xB1 = quad_perm(1,0,3,2) = xor1,
// 0x4E = quad_perm(2,3,0,1) = xor2, 0x141 = ROW_HALF_MIRROR (i <-> 7-i within
// each aligned 8-lane half-row; valid 3rd stage after xor1+xor2).
template<int CTRL>
static __device__ __forceinline__ float dpp_xadd(float x) {
    const int t = __builtin_amdgcn_update_dpp(
        0, __builtin_bit_cast(int, x), CTRL, 0xF, 0xF, true);
    return x + __builtin_bit_cast(float, t);
}
static __device__ __forceinline__ float og_allsum(float l) {
    l = dpp_xadd<0xB1>(l);
    l = dpp_xadd<0x4E>(l);
    l = dpp_xadd<0x141>(l);
    return l;
}

namespace {
constexpr int Bdim = 256;
constexpr int Rdim = 1152;
constexpr int Cdim = 10;
constexpr int Odim = 16;
constexpr int Idim = 8;
constexpr int CO   = 160;

constexpr int Rpad  = 1280;  // zero-padded R (padded rows: u=0 -> exact no-op)
constexpr int RPC   = 10;    // rows per chunk
constexpr int NPAIR = 5;     // staged row-pairs per chunk
constexpr int NCH   = 128;   // chunks
constexpr int NSP   = 32;    // s_part slices (4 chunks reduced in-block)
constexpr int WROW  = Cdim * Odim * Idim;   // 1280 f16 per W row
}

// f32 -> f16 with zero padding. W16: [Rpad][WROW]; X16t: [Rpad][Bdim][Idim].
__global__ __launch_bounds__(256)
void conv_wx(const float* __restrict__ W, const float* __restrict__ x,
             _Float16* __restrict__ W16, _Float16* __restrict__ X16)
{
    constexpr int NW4 = Rpad * WROW / 4;          // 409600 h4 slots
    constexpr int NX4 = Rpad * Bdim * Idim / 4;   // 655360 h4 slots
    const int i = blockIdx.x * 256 + threadIdx.x;
    if (i < NW4) {
        const int r = i / (WROW / 4);
        h4 o = { (_Float16)0.f, (_Float16)0.f, (_Float16)0.f, (_Float16)0.f };
        if (r < Rdim) {
            const float4 v = reinterpret_cast<const float4*>(W)[i];
            o = { (_Float16)v.x, (_Float16)v.y, (_Float16)v.z, (_Float16)v.w };
        }
        reinterpret_cast<h4*>(W16)[i] = o;
    } else if (i < NW4 + NX4) {
        const int j    = i - NW4;                 // [Rpad][Bdim][2] h4 slots
        const int r    = j / (Bdim * 2);
        const int rem  = j - r * (Bdim * 2);
        const int b    = rem >> 1;
        const int half = rem & 1;
        h4 o = { (_Float16)0.f, (_Float16)0.f, (_Float16)0.f, (_Float16)0.f };
        if (r < Rdim) {
            const float4 v = reinterpret_cast<const float4*>(x)
                [((size_t)b * Rdim + r) * 2 + half];
            o = { (_Float16)v.x, (_Float16)v.y, (_Float16)v.z, (_Float16)v.w };
        }
        reinterpret_cast<h4*>(X16)[j] = o;
    }
}

// Stage one W row-pair (2560 f16 = 5 KB) linearly into this wave's LDS buffer.
__device__ __forceinline__ void stagepair(const _Float16* __restrict__ src,
                                          _Float16* dst, int lane)
{
#pragma unroll
    for (int k = 0; k < 5; ++k) {
        const _Float16* s = src + (size_t)(k * 64 + lane) * 8;   // 16B granule
        _Float16* d = dst + k * 512;                             // wave-uniform
        __builtin_amdgcn_global_load_lds((const __attribute__((address_space(1))) void*)s,
                                         (__attribute__((address_space(3))) void*)d,
                                         16, 0, 0);
    }
}

template<bool FIRST>
__global__ __launch_bounds__(256)
void caps_iter(const _Float16* __restrict__ X16, const _Float16* __restrict__ W16,
               const float* __restrict__ Vsum, float* __restrict__ s_part)
{
    __shared__ __align__(16) _Float16 Wstage[4][2][2560];   // 40960 B exactly

    const int tid  = threadIdx.x;
    const int wv   = tid >> 6;
    const int lane = tid & 63;
    const int og   = lane & 7;          // o-group: o = og*2, og*2+1
    const int bl   = lane >> 3;         // 0..7; batches b0 = bg*16+bl, b1 = b0+8

    const int quad   = blockIdx.x;      // 0..31 (same quad -> same XCD)
    const int bgroup = blockIdx.y;      // 0..15
    const int chunk  = quad * 4 + wv;   // 0..127
    const int r0     = chunk * RPC;
    const int b0     = bgroup * 16 + bl;
    const int b1     = b0 + 8;

    // v (= Vsum) registers for both batches, all c, o = og*2 / og*2+1
    float va0[Cdim], vb0[Cdim], va1[Cdim], vb1[Cdim];
    if constexpr (!FIRST) {
#pragma unroll
        for (int c = 0; c < Cdim; ++c) {
            const float2 p = *reinterpret_cast<const float2*>(
                Vsum + (size_t)b0 * CO + c * Odim + og * 2);
            va0[c] = p.x; vb0[c] = p.y;
            const float2 q = *reinterpret_cast<const float2*>(
                Vsum + (size_t)b1 * CO + c * Odim + og * 2);
            va1[c] = q.x; vb1[c] = q.y;
        }
    }

    float sA0[Cdim], sA1[Cdim], sB0[Cdim], sB1[Cdim];
#pragma unroll
    for (int c = 0; c < Cdim; ++c) { sA0[c] = 0.f; sA1[c] = 0.f; sB0[c] = 0.f; sB1[c] = 0.f; }

    const _Float16* Wr = W16 + (size_t)r0 * WROW;
    _Float16* const st0 = &Wstage[wv][0][0];
    _Float16* const st1 = &Wstage[wv][1][0];

    stagepair(Wr, st0, lane);                 // prologue: pair 0
    uint4 xA0, xA1, xB0, xB1;                 // x[rl][t]
    {
        const _Float16* xr0 = X16 + ((size_t)(r0 + 0) * Bdim) * Idim;
        const _Float16* xr1 = X16 + ((size_t)(r0 + 1) * Bdim) * Idim;
        xA0 = *reinterpret_cast<const uint4*>(xr0 + b0 * Idim);
        xB0 = *reinterpret_cast<const uint4*>(xr0 + b1 * Idim);
        xA1 = *reinterpret_cast<const uint4*>(xr1 + b0 * Idim);
        xB1 = *reinterpret_cast<const uint4*>(xr1 + b1 * Idim);
    }

    for (int p = 0; p < NPAIR; ++p) {
        // this pair's stage + x are the only outstanding VMEM of this wave
        asm volatile("s_waitcnt vmcnt(0)" ::: "memory");

        const _Float16* stcur = (p & 1) ? st1 : st0;
        _Float16* stnxt = (p & 1) ? st0 : st1;
        uint4 nA0, nA1, nB0, nB1;
        if (p + 1 < NPAIR) {
            stagepair(Wr + (size_t)(p + 1) * 2 * WROW, stnxt, lane);
            const int rn = r0 + (p + 1) * 2;
            const _Float16* xr0 = X16 + ((size_t)(rn + 0) * Bdim) * Idim;
            const _Float16* xr1 = X16 + ((size_t)(rn + 1) * Bdim) * Idim;
            nA0 = *reinterpret_cast<const uint4*>(xr0 + b0 * Idim);
            nB0 = *reinterpret_cast<const uint4*>(xr0 + b1 * Idim);
            nA1 = *reinterpret_cast<const uint4*>(xr1 + b0 * Idim);
            nB1 = *reinterpret_cast<const uint4*>(xr1 + b1 * Idim);
        }

#pragma unroll
        for (int rl = 0; rl < 2; ++rl) {
            const uint4 xva = rl ? xA1 : xA0;   // batch b0
            const uint4 xvb = rl ? xB1 : xB0;   // batch b1
            const h2 a0 = BCH2(xva.x), a1 = BCH2(xva.y), a2 = BCH2(xva.z), a3 = BCH2(xva.w);
            const h2 b0h = BCH2(xvb.x), b1h = BCH2(xvb.y), b2h = BCH2(xvb.z), b3h = BCH2(xvb.w);

            // W granules for this lane's 2 o's; one LDS read feeds both batches
            const _Float16* wbase = stcur + rl * WROW + og * 16;
            float uA0[Cdim], uA1[Cdim], uB0[Cdim], uB1[Cdim];
#pragma unroll
            for (int c = 0; c < Cdim; ++c) {
                const uint4* wp = reinterpret_cast<const uint4*>(wbase + c * (Odim * Idim));
                const uint4 w0 = wp[0], w1 = wp[1];
                float t;
                t = FDOT2(BCH2(w0.x), a0, 0.f);  t = FDOT2(BCH2(w0.y), a1, t);
                t = FDOT2(BCH2(w0.z), a2, t);    uA0[c] = FDOT2(BCH2(w0.w), a3, t);
                t = FDOT2(BCH2(w1.x), a0, 0.f);  t = FDOT2(BCH2(w1.y), a1, t);
                t = FDOT2(BCH2(w1.z), a2, t);    uA1[c] = FDOT2(BCH2(w1.w), a3, t);
                t = FDOT2(BCH2(w0.x), b0h, 0.f); t = FDOT2(BCH2(w0.y), b1h, t);
                t = FDOT2(BCH2(w0.z), b2h, t);   uB0[c] = FDOT2(BCH2(w0.w), b3h, t);
                t = FDOT2(BCH2(w1.x), b0h, 0.f); t = FDOT2(BCH2(w1.y), b1h, t);
                t = FDOT2(BCH2(w1.z), b2h, t);   uB1[c] = FDOT2(BCH2(w1.w), b3h, t);
            }

            if constexpr (FIRST) {
#pragma unroll
                for (int c = 0; c < Cdim; ++c) {
                    sA0[c] += 0.1f * uA0[c];  sA1[c] += 0.1f * uA1[c];
                    sB0[c] += 0.1f * uB0[c];  sB1[c] += 0.1f * uB1[c];
                }
            } else {
                float eA[Cdim], eB[Cdim];
                float sumA = 0.f, sumB = 0.f;
#pragma unroll
                for (int c = 0; c < Cdim; ++c) {
                    float lA = uA0[c] * va0[c] + uA1[c] * vb0[c];
                    lA = og_allsum(lA);
                    eA[c] = __expf(lA);  sumA += eA[c];
                    float lB = uB0[c] * va1[c] + uB1[c] * vb1[c];
                    lB = og_allsum(lB);
                    eB[c] = __expf(lB);  sumB += eB[c];
                }
                const float rA = FRCP(sumA), rB = FRCP(sumB);
#pragma unroll
                for (int c = 0; c < Cdim; ++c) {
                    const float cwA = eA[c] * rA;
                    sA0[c] += cwA * uA0[c];  sA1[c] += cwA * uA1[c];
                    const float cwB = eB[c] * rB;
                    sB0[c] += cwB * uB0[c];  sB1[c] += cwB * uB1[c];
                }
            }
        }

        if (p + 1 < NPAIR) { xA0 = nA0; xA1 = nA1; xB0 = nB0; xB1 = nB1; }
    }

    // ---- in-block reduce over the 4 waves' chunks (reuse Wstage: [4][16][160])
    __syncthreads();
    float* red = reinterpret_cast<float*>(&Wstage[0][0][0]);
    {
        float* p0 = red + (wv * 16 + bl) * CO + og * 2;       // batch b0 row
        float* p1 = red + (wv * 16 + bl + 8) * CO + og * 2;   // batch b1 row
#pragma unroll
        for (int c = 0; c < Cdim; ++c) {
            *reinterpret_cast<float2*>(p0 + c * Odim) = make_float2(sA0[c], sA1[c]);
            *reinterpret_cast<float2*>(p1 + c * Odim) = make_float2(sB0[c], sB1[c]);
        }
    }
    __syncthreads();
#pragma unroll
    for (int k = 0; k < 10; ++k) {
        const int j = k * 256 + tid;         // 0..2559 = 16 b x 160 co
        const float t = red[j] + red[j + 2560] + red[j + 5120] + red[j + 7680];
        const int b2 = j / CO;
        const int co = j - b2 * CO;
        s_part[((size_t)quad * Bdim + bgroup * 16 + b2) * CO + co] = t;
    }
}

// Sum the NSP partials, squash; MODE 0: Vsum = v (it0, replaces memset),
// MODE 1: Vsum += v, MODE 2: out = v.
template<int MODE>
__global__ __launch_bounds__(256)
void caps_reduce(const float* __restrict__ s_part, float* __restrict__ Vsum,
                 float* __restrict__ out)
{
    const int idx = blockIdx.x * 256 + threadIdx.x;   // < 40960 = B*C*O
    float s = 0.f;
#pragma unroll 8
    for (int k = 0; k < NSP; ++k) s += s_part[(size_t)k * (Bdim * CO) + idx];

    float ssq = s * s;
    ssq += __shfl_xor(ssq, 1);
    ssq += __shfl_xor(ssq, 2);
    ssq += __shfl_xor(ssq, 4);
    ssq += __shfl_xor(ssq, 8);

    const float mag = sqrtf(ssq + 1e-8f);
    const float v = ssq / (1.f + ssq) * s / (mag + 1e-8f);

    if constexpr (MODE == 2) out[idx] = v;
    else if constexpr (MODE == 1) Vsum[idx] += v;
    else Vsum[idx] = v;
}

extern "C" void kernel_launch(void* const* d_in, const int* in_sizes, int n_in,
                              void* d_out, int out_size, void* d_ws, size_t ws_size,
                              hipStream_t stream)
{
    const float* x = (const float*)d_in[0];   // [256,1152,8]
    const float* W = (const float*)d_in[1];   // [1152,10,16,8]
    float* out = (float*)d_out;               // [256,10,16]

    float* s_part = (float*)d_ws;                           // 32*256*160 f32
    float* Vsum   = s_part + (size_t)NSP * Bdim * CO;       // 256*160 f32
    _Float16* W16 = (_Float16*)(Vsum + Bdim * CO);          // 1280*1280 f16
    _Float16* X16 = W16 + (size_t)Rpad * WROW;              // 1280*256*8 f16

    // (409600 + 655360) / 256 = 4160 blocks, exact
    conv_wx<<<dim3(4160), dim3(256), 0, stream>>>(W, x, W16, X16);

    const dim3 gi(NSP, Bdim / 16);   // (32, 16); quad fastest -> XCD affinity
    const dim3 bi(256);
    const dim3 gr((Bdim * CO) / 256);
    const dim3 br(256);

    // it 0
    caps_iter<true><<<gi, bi, 0, stream>>>(X16, W16, Vsum, s_part);
    caps_reduce<0><<<gr, br, 0, stream>>>(s_part, Vsum, out);
    // it 1
    caps_iter<false><<<gi, bi, 0, stream>>>(X16, W16, Vsum, s_part);
    caps_reduce<1><<<gr, br, 0, stream>>>(s_part, Vsum, out);
    // it 2 (final -> d_out)
    caps_iter<false><<<gi, bi, 0, stream>>>(X16, W16, Vsum, s_part);
    caps_reduce<2><<<gr, br, 0, stream>>>(s_part, Vsum, out);
}

// Round 12
// 100.315 us; speedup vs baseline: 1.3146x; 1.0101x over previous
//
#include <hip/hip_runtime.h>
#include <math.h>

// DigitCaps dynamic routing, B=256 R=1152 C=10 OUT=16 IN=8, fp32 in/out.
// Identity: b_ij(t) = dot(u_hat, Vsum), Vsum = sum of previous v -> never
// store b_ij/u_hat; recompute u_hat from W16 each iteration.
//
// 7-launch structure (graph-safe): conv_wx + 3 x (caps_iter + caps_reduce).
// caps_iter: wave-private 3-buffer LDS W staging (global_load_lds, depth-2
// pipeline, counted vmcnt(5)), T=2 batches/thread, W ds_reads bulk-loaded
// into a wreg register block (10 b128 in flight -> LDS latency paid once per
// 5-c group), DPP og-lane reduction (zero DS ops in softmax), barrier-free
// main loop; in-block reduce over the 4 waves.
//
// ws: s_part[32][256][160] (5.24MB) + Vsum (0.16MB) + W16[1280][1280] f16
//     (3.28MB) + X16t[1280][256][8] f16 (5.24MB) = 13.9MB

typedef _Float16 h2 __attribute__((ext_vector_type(2)));
typedef _Float16 h4 __attribute__((ext_vector_type(4)));

#if __has_builtin(__builtin_amdgcn_fdot2)
#define FDOT2(a, b, c) __builtin_amdgcn_fdot2((a), (b), (c), false)
#else
static __device__ __forceinline__ float FDOT2(h2 a, h2 b, float c) {
    return c + (float)a.x * (float)b.x + (float)a.y * (float)b.y;
}
#endif

#if __has_builtin(__builtin_amdgcn_rcpf)
#define FRCP(x) __builtin_amdgcn_rcpf(x)
#else
#define FRCP(x) (1.0f / (x))
#endif

#define BCH2(u) __builtin_bit_cast(h2, (u))

// cross-lane add via DPP (VALU, not DS). 0xB1 = quad_perm xor1, 0x4E = xor2,
// 0x141 = ROW_HALF_MIRROR (completes the 8-lane sum). Verified R9/R10.
template<int CTRL>
static __device__ __forceinline__ float dpp_xadd(float x) {
    const int t = __builtin_amdgcn_update_dpp(
        0, __builtin_bit_cast(int, x), CTRL, 0xF, 0xF, true);
    return x + __builtin_bit_cast(float, t);
}
static __device__ __forceinline__ float og_allsum(float l) {
    l = dpp_xadd<0xB1>(l);
    l = dpp_xadd<0x4E>(l);
    l = dpp_xadd<0x141>(l);
    return l;
}

namespace {
constexpr int Bdim = 256;
constexpr int Rdim = 1152;
constexpr int Cdim = 10;
constexpr int Odim = 16;
constexpr int Idim = 8;
constexpr int CO   = 160;

constexpr int Rpad  = 1280;  // zero-padded R (pad rows: u=0 -> exact no-op)
constexpr int RPC   = 10;    // rows per chunk
constexpr int NPAIR = 5;     // row-pairs per chunk
constexpr int NSP   = 32;    // s_part slices
constexpr int WROW  = Cdim * Odim * Idim;   // 1280 f16 per W row
}

// f32 -> f16 with zero padding. W16: [Rpad][WROW]; X16t: [Rpad][Bdim][Idim].
__global__ __launch_bounds__(256)
void conv_wx(const float* __restrict__ W, const float* __restrict__ x,
             _Float16* __restrict__ W16, _Float16* __restrict__ X16)
{
    constexpr int NW4 = Rpad * WROW / 4;          // 409600 h4 slots
    constexpr int NX4 = Rpad * Bdim * Idim / 4;   // 655360 h4 slots
    const int i = blockIdx.x * 256 + threadIdx.x;
    if (i < NW4) {
        const int r = i / (WROW / 4);
        h4 o = { (_Float16)0.f, (_Float16)0.f, (_Float16)0.f, (_Float16)0.f };
        if (r < Rdim) {
            const float4 v = reinterpret_cast<const float4*>(W)[i];
            o = { (_Float16)v.x, (_Float16)v.y, (_Float16)v.z, (_Float16)v.w };
        }
        reinterpret_cast<h4*>(W16)[i] = o;
    } else if (i < NW4 + NX4) {
        const int j    = i - NW4;                 // [Rpad][Bdim][2] h4 slots
        const int r    = j / (Bdim * 2);
        const int rem  = j - r * (Bdim * 2);
        const int b    = rem >> 1;
        const int half = rem & 1;
        h4 o = { (_Float16)0.f, (_Float16)0.f, (_Float16)0.f, (_Float16)0.f };
        if (r < Rdim) {
            const float4 v = reinterpret_cast<const float4*>(x)
                [((size_t)b * Rdim + r) * 2 + half];
            o = { (_Float16)v.x, (_Float16)v.y, (_Float16)v.z, (_Float16)v.w };
        }
        reinterpret_cast<h4*>(X16)[j] = o;
    }
}

// Stage one W row-pair (2560 f16 = 5 KB) linearly into a wave-private buffer.
__device__ __forceinline__ void stagepair(const _Float16* __restrict__ src,
                                          _Float16* dst, int lane)
{
#pragma unroll
    for (int k = 0; k < 5; ++k) {
        const _Float16* s = src + (size_t)(k * 64 + lane) * 8;   // 16B granule
        _Float16* d = dst + k * 512;                             // wave-uniform
        __builtin_amdgcn_global_load_lds((const __attribute__((address_space(1))) void*)s,
                                         (__attribute__((address_space(3))) void*)d,
                                         16, 0, 0);
    }
}

template<bool FIRST>
__global__ __launch_bounds__(256)
void caps_iter(const _Float16* __restrict__ X16, const _Float16* __restrict__ W16,
               const float* __restrict__ Vsum, float* __restrict__ s_part)
{
    __shared__ __align__(16) _Float16 Wst[4][3][2560];   // 61440 B -> 2 blk/CU

    const int tid  = threadIdx.x;
    const int wv   = tid >> 6;
    const int lane = tid & 63;
    const int og   = lane & 7;          // o-group: o = og*2, og*2+1
    const int bl   = lane >> 3;         // 0..7

    const int quad = blockIdx.x;        // 0..31 (XCD affinity group)
    const int bgrp = blockIdx.y;        // 0..15
    const int chunk = quad * 4 + wv;    // 0..127
    const int r0    = chunk * RPC;
    const int b0    = bgrp * 16 + bl;
    const int b1    = b0 + 8;

    float va0[Cdim], vb0[Cdim], va1[Cdim], vb1[Cdim];
    if constexpr (!FIRST) {
#pragma unroll
        for (int c = 0; c < Cdim; ++c) {
            const float2 p = *reinterpret_cast<const float2*>(
                Vsum + (size_t)b0 * CO + c * Odim + og * 2);
            va0[c] = p.x; vb0[c] = p.y;
            const float2 q = *reinterpret_cast<const float2*>(
                Vsum + (size_t)b1 * CO + c * Odim + og * 2);
            va1[c] = q.x; vb1[c] = q.y;
        }
    }

    float sA0[Cdim], sA1[Cdim], sB0[Cdim], sB1[Cdim];
#pragma unroll
    for (int c = 0; c < Cdim; ++c) { sA0[c]=0.f; sA1[c]=0.f; sB0[c]=0.f; sB1[c]=0.f; }

    const _Float16* Wr = W16 + (size_t)r0 * WROW;

    // prologue: S(0), X(0), S(1)  -> 14 outstanding VMEM
    stagepair(Wr, &Wst[wv][0][0], lane);
    uint4 xc0, xc1, xc2, xc3;
    {
        const _Float16* xr = X16 + (size_t)r0 * (Bdim * Idim);
        xc0 = *reinterpret_cast<const uint4*>(xr + b0 * Idim);
        xc1 = *reinterpret_cast<const uint4*>(xr + b1 * Idim);
        xc2 = *reinterpret_cast<const uint4*>(xr + (Bdim * Idim) + b0 * Idim);
        xc3 = *reinterpret_cast<const uint4*>(xr + (Bdim * Idim) + b1 * Idim);
    }
    stagepair(Wr + 2 * WROW, &Wst[wv][1][0], lane);

    for (int p = 0; p < NPAIR; ++p) {
        // drain stage(p)+x(p); keep stage(p+1) [5 newest] in flight
        if (p + 1 < NPAIR)
            asm volatile("s_waitcnt vmcnt(5)" ::: "memory");
        else
            asm volatile("s_waitcnt vmcnt(0)" ::: "memory");

        const _Float16* stcur = &Wst[wv][p % 3][0];

        uint4 xn0, xn1, xn2, xn3;
        if (p + 1 < NPAIR) {                 // issue x(p+1) first...
            const _Float16* xr = X16 + (size_t)(r0 + (p + 1) * 2) * (Bdim * Idim);
            xn0 = *reinterpret_cast<const uint4*>(xr + b0 * Idim);
            xn1 = *reinterpret_cast<const uint4*>(xr + b1 * Idim);
            xn2 = *reinterpret_cast<const uint4*>(xr + (Bdim * Idim) + b0 * Idim);
            xn3 = *reinterpret_cast<const uint4*>(xr + (Bdim * Idim) + b1 * Idim);
        }
        if (p + 2 < NPAIR)                   // ...then stage(p+2)
            stagepair(Wr + (size_t)(p + 2) * 2 * WROW, &Wst[wv][(p + 2) % 3][0], lane);

#pragma unroll
        for (int rl = 0; rl < 2; ++rl) {
            const uint4 xva = rl ? xc2 : xc0;    // batch b0
            const uint4 xvb = rl ? xc3 : xc1;    // batch b1
            const h2 a0 = BCH2(xva.x), a1 = BCH2(xva.y), a2 = BCH2(xva.z), a3 = BCH2(xva.w);
            const h2 e0 = BCH2(xvb.x), e1 = BCH2(xvb.y), e2 = BCH2(xvb.z), e3 = BCH2(xvb.w);

            const _Float16* wbase = stcur + rl * WROW + og * 16;
            float uA0[Cdim], uA1[Cdim], uB0[Cdim], uB1[Cdim];
#pragma unroll
            for (int g = 0; g < 2; ++g) {
                // bulk-load 10 b128 into registers -> LDS latency paid once
                uint4 wreg[10];
#pragma unroll
                for (int c5 = 0; c5 < 5; ++c5) {
                    const uint4* wp = reinterpret_cast<const uint4*>(
                        wbase + (g * 5 + c5) * (Odim * Idim));
                    wreg[2 * c5]     = wp[0];
                    wreg[2 * c5 + 1] = wp[1];
                }
#pragma unroll
                for (int c5 = 0; c5 < 5; ++c5) {
                    const int c = g * 5 + c5;
                    const uint4 w0 = wreg[2 * c5], w1 = wreg[2 * c5 + 1];
                    float t;
                    t = FDOT2(BCH2(w0.x), a0, 0.f);  t = FDOT2(BCH2(w0.y), a1, t);
                    t = FDOT2(BCH2(w0.z), a2, t);    uA0[c] = FDOT2(BCH2(w0.w), a3, t);
                    t = FDOT2(BCH2(w1.x), a0, 0.f);  t = FDOT2(BCH2(w1.y), a1, t);
                    t = FDOT2(BCH2(w1.z), a2, t);    uA1[c] = FDOT2(BCH2(w1.w), a3, t);
                    t = FDOT2(BCH2(w0.x), e0, 0.f);  t = FDOT2(BCH2(w0.y), e1, t);
                    t = FDOT2(BCH2(w0.z), e2, t);    uB0[c] = FDOT2(BCH2(w0.w), e3, t);
                    t = FDOT2(BCH2(w1.x), e0, 0.f);  t = FDOT2(BCH2(w1.y), e1, t);
                    t = FDOT2(BCH2(w1.z), e2, t);    uB1[c] = FDOT2(BCH2(w1.w), e3, t);
                }
            }

            if constexpr (FIRST) {
#pragma unroll
                for (int c = 0; c < Cdim; ++c) {
                    sA0[c] += 0.1f * uA0[c];  sA1[c] += 0.1f * uA1[c];
                    sB0[c] += 0.1f * uB0[c];  sB1[c] += 0.1f * uB1[c];
                }
            } else {
                float eA[Cdim], eB[Cdim];
                float sumA = 0.f, sumB = 0.f;
#pragma unroll
                for (int c = 0; c < Cdim; ++c) {
                    float lA = uA0[c] * va0[c] + uA1[c] * vb0[c];
                    lA = og_allsum(lA);
                    eA[c] = __expf(lA);  sumA += eA[c];
                    float lB = uB0[c] * va1[c] + uB1[c] * vb1[c];
                    lB = og_allsum(lB);
                    eB[c] = __expf(lB);  sumB += eB[c];
                }
                const float rA = FRCP(sumA), rB = FRCP(sumB);
#pragma unroll
                for (int c = 0; c < Cdim; ++c) {
                    const float cwA = eA[c] * rA;
                    sA0[c] += cwA * uA0[c];  sA1[c] += cwA * uA1[c];
                    const float cwB = eB[c] * rB;
                    sB0[c] += cwB * uB0[c];  sB1[c] += cwB * uB1[c];
                }
            }
        }

        if (p + 1 < NPAIR) { xc0 = xn0; xc1 = xn1; xc2 = xn2; xc3 = xn3; }
    }

    // ---- in-block reduce over 4 waves (reuse Wst as f32 [4][16][160])
    __syncthreads();
    float* red = reinterpret_cast<float*>(&Wst[0][0][0]);
    {
        float* p0 = red + (wv * 16 + bl) * CO + og * 2;
        float* p1 = red + (wv * 16 + bl + 8) * CO + og * 2;
#pragma unroll
        for (int c = 0; c < Cdim; ++c) {
            *reinterpret_cast<float2*>(p0 + c * Odim) = make_float2(sA0[c], sA1[c]);
            *reinterpret_cast<float2*>(p1 + c * Odim) = make_float2(sB0[c], sB1[c]);
        }
    }
    __syncthreads();
#pragma unroll
    for (int k = 0; k < 10; ++k) {
        const int j = k * 256 + tid;          // 0..2559 = 16 b x 160 co
        const float t = red[j] + red[j + 2560] + red[j + 5120] + red[j + 7680];
        const int b2 = j / CO;
        const int co = j - b2 * CO;
        s_part[((size_t)quad * Bdim + bgrp * 16 + b2) * CO + co] = t;
    }
}

// Sum the NSP partials, squash; MODE 0: Vsum = v (replaces memset),
// MODE 1: Vsum += v, MODE 2: out = v.
template<int MODE>
__global__ __launch_bounds__(256)
void caps_reduce(const float* __restrict__ s_part, float* __restrict__ Vsum,
                 float* __restrict__ out)
{
    const int idx = blockIdx.x * 256 + threadIdx.x;   // < 40960 = B*C*O
    float s = 0.f;
#pragma unroll 8
    for (int k = 0; k < NSP; ++k) s += s_part[(size_t)k * (Bdim * CO) + idx];

    float ssq = s * s;
    ssq += __shfl_xor(ssq, 1);
    ssq += __shfl_xor(ssq, 2);
    ssq += __shfl_xor(ssq, 4);
    ssq += __shfl_xor(ssq, 8);

    const float mag = sqrtf(ssq + 1e-8f);
    const float v = ssq / (1.f + ssq) * s / (mag + 1e-8f);

    if constexpr (MODE == 2) out[idx] = v;
    else if constexpr (MODE == 1) Vsum[idx] += v;
    else Vsum[idx] = v;
}

extern "C" void kernel_launch(void* const* d_in, const int* in_sizes, int n_in,
                              void* d_out, int out_size, void* d_ws, size_t ws_size,
                              hipStream_t stream)
{
    const float* x = (const float*)d_in[0];   // [256,1152,8]
    const float* W = (const float*)d_in[1];   // [1152,10,16,8]
    float* out = (float*)d_out;               // [256,10,16]

    float* s_part = (float*)d_ws;                           // 32*256*160 f32
    float* Vsum   = s_part + (size_t)NSP * Bdim * CO;       // 256*160 f32
    _Float16* W16 = (_Float16*)(Vsum + Bdim * CO);          // 1280*1280 f16
    _Float16* X16 = W16 + (size_t)Rpad * WROW;              // 1280*256*8 f16

    // (409600 + 655360) / 256 = 4160 blocks, exact
    conv_wx<<<dim3(4160), dim3(256), 0, stream>>>(W, x, W16, X16);

    const dim3 gi(NSP, Bdim / 16);   // (32, 16); quad fastest -> XCD affinity
    const dim3 bi(256);
    const dim3 gr((Bdim * CO) / 256);
    const dim3 br(256);

    // it 0
    caps_iter<true><<<gi, bi, 0, stream>>>(X16, W16, Vsum, s_part);
    caps_reduce<0><<<gr, br, 0, stream>>>(s_part, Vsum, out);
    // it 1
    caps_iter<false><<<gi, bi, 0, stream>>>(X16, W16, Vsum, s_part);
    caps_reduce<1><<<gr, br, 0, stream>>>(s_part, Vsum, out);
    // it 2 (final -> d_out)
    caps_iter<false><<<gi, bi, 0, stream>>>(X16, W16, Vsum, s_part);
    caps_reduce<2><<<gr, br, 0, stream>>>(s_part, Vsum, out);
}

// Round 13
// 97.705 us; speedup vs baseline: 1.3498x; 1.0267x over previous
//
#include <hip/hip_runtime.h>
#include <math.h>

// DigitCaps dynamic routing, B=256 R=1152 C=10 OUT=16 IN=8, fp32 in/out.
// Identity: b_ij(t) = dot(u_hat, Vsum), Vsum = sum of previous v -> never
// store b_ij/u_hat; recompute u_hat from W16 each iteration.
//
// 7-launch structure: conv_w (W f32->f16 only) + 3 x (caps_iter + caps_reduce).
// caps_iter reads x DIRECTLY from the f32 input (no transpose pass, no X16):
// rows r,r+1 are contiguous 64B per batch; cvt_pkrtz packs to f16 in-kernel.
// Padded rows r>=1152: x address clamped to row 1150, W16 zero rows give u=0
// -> exactly zero contribution (softmax is per-r over c). T=2 batches/thread,
// wave-private 2-buffer LDS W staging (40KB total -> 4 blocks/CU capacity),
// depth-1 pipeline with counted vmcnt, DPP og-lane softmax reduction (no DS),
// barrier-free main loop, in-block reduce over the 4 waves.
//
// ws: s_part[32][256][160] (5.24MB) + Vsum (0.16MB) + W16[1280][1280] f16
//     (3.28MB) = 8.7MB

typedef _Float16 h2 __attribute__((ext_vector_type(2)));
typedef _Float16 h4 __attribute__((ext_vector_type(4)));

#if __has_builtin(__builtin_amdgcn_fdot2)
#define FDOT2(a, b, c) __builtin_amdgcn_fdot2((a), (b), (c), false)
#else
static __device__ __forceinline__ float FDOT2(h2 a, h2 b, float c) {
    return c + (float)a.x * (float)b.x + (float)a.y * (float)b.y;
}
#endif

static __device__ __forceinline__ h2 CVTPK(float a, float b) {
#if __has_builtin(__builtin_amdgcn_cvt_pkrtz)
    return __builtin_bit_cast(h2, __builtin_amdgcn_cvt_pkrtz(a, b));
#else
    h2 r; r.x = (_Float16)a; r.y = (_Float16)b; return r;
#endif
}

#if __has_builtin(__builtin_amdgcn_rcpf)
#define FRCP(x) __builtin_amdgcn_rcpf(x)
#else
#define FRCP(x) (1.0f / (x))
#endif

#define BCH2(u) __builtin_bit_cast(h2, (u))

// cross-lane add via DPP (VALU, not DS). 0xB1 = quad_perm xor1, 0x4E = xor2,
// 0x141 = ROW_HALF_MIRROR (completes the 8-lane sum). Verified R9/R10/R12.
template<int CTRL>
static __device__ __forceinline__ float dpp_xadd(float x) {
    const int t = __builtin_amdgcn_update_dpp(
        0, __builtin_bit_cast(int, x), CTRL, 0xF, 0xF, true);
    return x + __builtin_bit_cast(float, t);
}
static __device__ __forceinline__ float og_allsum(float l) {
    l = dpp_xadd<0xB1>(l);
    l = dpp_xadd<0x4E>(l);
    l = dpp_xadd<0x141>(l);
    return l;
}

namespace {
constexpr int Bdim = 256;
constexpr int Rdim = 1152;
constexpr int Cdim = 10;
constexpr int Odim = 16;
constexpr int Idim = 8;
constexpr int CO   = 160;

constexpr int Rpad  = 1280;  // zero-padded R (pad rows: u=0 -> exact no-op)
constexpr int RPC   = 10;    // rows per chunk
constexpr int NPAIR = 5;     // row-pairs per chunk
constexpr int NSP   = 32;    // s_part slices
constexpr int WROW  = Cdim * Odim * Idim;   // 1280 f16 per W row
}

// f32 -> f16 W with zero padding to Rpad rows. Coalesced both sides.
__global__ __launch_bounds__(256)
void conv_w(const float* __restrict__ W, _Float16* __restrict__ W16)
{
    const int i = blockIdx.x * 256 + threadIdx.x;    // < 409600
    const int r = i / (WROW / 4);
    h4 o = { (_Float16)0.f, (_Float16)0.f, (_Float16)0.f, (_Float16)0.f };
    if (r < Rdim) {
        const float4 v = reinterpret_cast<const float4*>(W)[i];
        o = { (_Float16)v.x, (_Float16)v.y, (_Float16)v.z, (_Float16)v.w };
    }
    reinterpret_cast<h4*>(W16)[i] = o;
}

// Stage one W row-pair (2560 f16 = 5 KB) linearly into a wave-private buffer.
__device__ __forceinline__ void stagepair(const _Float16* __restrict__ src,
                                          _Float16* dst, int lane)
{
#pragma unroll
    for (int k = 0; k < 5; ++k) {
        const _Float16* s = src + (size_t)(k * 64 + lane) * 8;   // 16B granule
        _Float16* d = dst + k * 512;                             // wave-uniform
        __builtin_amdgcn_global_load_lds((const __attribute__((address_space(1))) void*)s,
                                         (__attribute__((address_space(3))) void*)d,
                                         16, 0, 0);
    }
}

template<bool FIRST>
__global__ __launch_bounds__(256)
void caps_iter(const float* __restrict__ xf, const _Float16* __restrict__ W16,
               const float* __restrict__ Vsum, float* __restrict__ s_part)
{
    __shared__ __align__(16) _Float16 Wst[4][2][2560];   // 40960 B exactly

    const int tid  = threadIdx.x;
    const int wv   = tid >> 6;
    const int lane = tid & 63;
    const int og   = lane & 7;          // o-group: o = og*2, og*2+1
    const int bl   = lane >> 3;         // 0..7

    const int quad = blockIdx.x;        // 0..31 (XCD affinity group)
    const int bgrp = blockIdx.y;        // 0..15
    const int chunk = quad * 4 + wv;    // 0..127
    const int r0    = chunk * RPC;
    const int b0    = bgrp * 16 + bl;
    const int b1    = b0 + 8;

    float va0[Cdim], vb0[Cdim], va1[Cdim], vb1[Cdim];
    if constexpr (!FIRST) {
#pragma unroll
        for (int c = 0; c < Cdim; ++c) {
            const float2 p = *reinterpret_cast<const float2*>(
                Vsum + (size_t)b0 * CO + c * Odim + og * 2);
            va0[c] = p.x; vb0[c] = p.y;
            const float2 q = *reinterpret_cast<const float2*>(
                Vsum + (size_t)b1 * CO + c * Odim + og * 2);
            va1[c] = q.x; vb1[c] = q.y;
        }
    }

    float sA0[Cdim], sA1[Cdim], sB0[Cdim], sB1[Cdim];
#pragma unroll
    for (int c = 0; c < Cdim; ++c) { sA0[c]=0.f; sA1[c]=0.f; sB0[c]=0.f; sB1[c]=0.f; }

    const _Float16* Wr = W16 + (size_t)r0 * WROW;
    const float* xb0 = xf + (size_t)b0 * (Rdim * Idim);
    const float* xb1 = xf + (size_t)b1 * (Rdim * Idim);

    // x row-pair base (clamped for padded rows; W16 zeros make u=0 there)
    auto xoff = [&](int p) -> int {
        int r = r0 + p * 2;
        return (r > Rdim - 2 ? Rdim - 2 : r) * Idim;
    };

    // prologue: stage(0) [5] + x(0) [8 float4 loads] -> 13 outstanding
    stagepair(Wr, &Wst[wv][0][0], lane);
    float4 xc[8];
    {
        const int o0 = xoff(0);
        xc[0] = *reinterpret_cast<const float4*>(xb0 + o0);
        xc[1] = *reinterpret_cast<const float4*>(xb0 + o0 + 4);
        xc[2] = *reinterpret_cast<const float4*>(xb0 + o0 + 8);
        xc[3] = *reinterpret_cast<const float4*>(xb0 + o0 + 12);
        xc[4] = *reinterpret_cast<const float4*>(xb1 + o0);
        xc[5] = *reinterpret_cast<const float4*>(xb1 + o0 + 4);
        xc[6] = *reinterpret_cast<const float4*>(xb1 + o0 + 8);
        xc[7] = *reinterpret_cast<const float4*>(xb1 + o0 + 12);
    }

    for (int p = 0; p < NPAIR; ++p) {
        // drain stage(p) [oldest 5]; keep x(p) [8] in flight (compiler waits
        // for the x registers right before their first use)
        asm volatile("s_waitcnt vmcnt(8)" ::: "memory");

        const _Float16* stcur = &Wst[wv][p & 1][0];

        float4 xn[8];
        if (p + 1 < NPAIR) {
            stagepair(Wr + (size_t)(p + 1) * 2 * WROW, &Wst[wv][(p + 1) & 1][0], lane);
            const int o1 = xoff(p + 1);
            xn[0] = *reinterpret_cast<const float4*>(xb0 + o1);
            xn[1] = *reinterpret_cast<const float4*>(xb0 + o1 + 4);
            xn[2] = *reinterpret_cast<const float4*>(xb0 + o1 + 8);
            xn[3] = *reinterpret_cast<const float4*>(xb0 + o1 + 12);
            xn[4] = *reinterpret_cast<const float4*>(xb1 + o1);
            xn[5] = *reinterpret_cast<const float4*>(xb1 + o1 + 4);
            xn[6] = *reinterpret_cast<const float4*>(xb1 + o1 + 8);
            xn[7] = *reinterpret_cast<const float4*>(xb1 + o1 + 12);
        }

#pragma unroll
        for (int rl = 0; rl < 2; ++rl) {
            // pack this row's x to f16 (batch A = b0, batch B = b1)
            const float4 pa0 = xc[rl * 2 + 0], pa1 = xc[rl * 2 + 1];
            const float4 pb0 = xc[rl * 2 + 4], pb1 = xc[rl * 2 + 5];
            const h2 a0 = CVTPK(pa0.x, pa0.y), a1 = CVTPK(pa0.z, pa0.w);
            const h2 a2 = CVTPK(pa1.x, pa1.y), a3 = CVTPK(pa1.z, pa1.w);
            const h2 e0 = CVTPK(pb0.x, pb0.y), e1 = CVTPK(pb0.z, pb0.w);
            const h2 e2 = CVTPK(pb1.x, pb1.y), e3 = CVTPK(pb1.z, pb1.w);

            const _Float16* wbase = stcur + rl * WROW + og * 16;
            float uA0[Cdim], uA1[Cdim], uB0[Cdim], uB1[Cdim];
#pragma unroll
            for (int c = 0; c < Cdim; ++c) {
                const uint4* wp = reinterpret_cast<const uint4*>(wbase + c * (Odim * Idim));
                const uint4 w0 = wp[0], w1 = wp[1];
                float t;
                t = FDOT2(BCH2(w0.x), a0, 0.f);  t = FDOT2(BCH2(w0.y), a1, t);
                t = FDOT2(BCH2(w0.z), a2, t);    uA0[c] = FDOT2(BCH2(w0.w), a3, t);
                t = FDOT2(BCH2(w1.x), a0, 0.f);  t = FDOT2(BCH2(w1.y), a1, t);
                t = FDOT2(BCH2(w1.z), a2, t);    uA1[c] = FDOT2(BCH2(w1.w), a3, t);
                t = FDOT2(BCH2(w0.x), e0, 0.f);  t = FDOT2(BCH2(w0.y), e1, t);
                t = FDOT2(BCH2(w0.z), e2, t);    uB0[c] = FDOT2(BCH2(w0.w), e3, t);
                t = FDOT2(BCH2(w1.x), e0, 0.f);  t = FDOT2(BCH2(w1.y), e1, t);
                t = FDOT2(BCH2(w1.z), e2, t);    uB1[c] = FDOT2(BCH2(w1.w), e3, t);
            }

            if constexpr (FIRST) {
#pragma unroll
                for (int c = 0; c < Cdim; ++c) {
                    sA0[c] += 0.1f * uA0[c];  sA1[c] += 0.1f * uA1[c];
                    sB0[c] += 0.1f * uB0[c];  sB1[c] += 0.1f * uB1[c];
                }
            } else {
                float eA[Cdim], eB[Cdim];
                float sumA = 0.f, sumB = 0.f;
#pragma unroll
                for (int c = 0; c < Cdim; ++c) {
                    float lA = uA0[c] * va0[c] + uA1[c] * vb0[c];
                    lA = og_allsum(lA);
                    eA[c] = __expf(lA);  sumA += eA[c];
                    float lB = uB0[c] * va1[c] + uB1[c] * vb1[c];
                    lB = og_allsum(lB);
                    eB[c] = __expf(lB);  sumB += eB[c];
                }
                const float rA = FRCP(sumA), rB = FRCP(sumB);
#pragma unroll
                for (int c = 0; c < Cdim; ++c) {
                    const float cwA = eA[c] * rA;
                    sA0[c] += cwA * uA0[c];  sA1[c] += cwA * uA1[c];
                    const float cwB = eB[c] * rB;
                    sB0[c] += cwB * uB0[c];  sB1[c] += cwB * uB1[c];
                }
            }
        }

        if (p + 1 < NPAIR) {
#pragma unroll
            for (int q = 0; q < 8; ++q) xc[q] = xn[q];
        }
    }

    // ---- in-block reduce over 4 waves (reuse Wst as f32 [4][16][160])
    __syncthreads();
    float* red = reinterpret_cast<float*>(&Wst[0][0][0]);
    {
        float* p0 = red + (wv * 16 + bl) * CO + og * 2;
        float* p1 = red + (wv * 16 + bl + 8) * CO + og * 2;
#pragma unroll
        for (int c = 0; c < Cdim; ++c) {
            *reinterpret_cast<float2*>(p0 + c * Odim) = make_float2(sA0[c], sA1[c]);
            *reinterpret_cast<float2*>(p1 + c * Odim) = make_float2(sB0[c], sB1[c]);
        }
    }
    __syncthreads();
#pragma unroll
    for (int k = 0; k < 10; ++k) {
        const int j = k * 256 + tid;          // 0..2559 = 16 b x 160 co
        const float t = red[j] + red[j + 2560] + red[j + 5120] + red[j + 7680];
        const int b2 = j / CO;
        const int co = j - b2 * CO;
        s_part[((size_t)quad * Bdim + bgrp * 16 + b2) * CO + co] = t;
    }
}

// Sum the NSP partials, squash; MODE 0: Vsum = v (replaces memset),
// MODE 1: Vsum += v, MODE 2: out = v.
template<int MODE>
__global__ __launch_bounds__(256)
void caps_reduce(const float* __restrict__ s_part, float* __restrict__ Vsum,
                 float* __restrict__ out)
{
    const int idx = blockIdx.x * 256 + threadIdx.x;   // < 40960 = B*C*O
    float s = 0.f;
#pragma unroll 8
    for (int k = 0; k < NSP; ++k) s += s_part[(size_t)k * (Bdim * CO) + idx];

    float ssq = s * s;
    ssq += __shfl_xor(ssq, 1);
    ssq += __shfl_xor(ssq, 2);
    ssq += __shfl_xor(ssq, 4);
    ssq += __shfl_xor(ssq, 8);

    const float mag = sqrtf(ssq + 1e-8f);
    const float v = ssq / (1.f + ssq) * s / (mag + 1e-8f);

    if constexpr (MODE == 2) out[idx] = v;
    else if constexpr (MODE == 1) Vsum[idx] += v;
    else Vsum[idx] = v;
}

extern "C" void kernel_launch(void* const* d_in, const int* in_sizes, int n_in,
                              void* d_out, int out_size, void* d_ws, size_t ws_size,
                              hipStream_t stream)
{
    const float* x = (const float*)d_in[0];   // [256,1152,8]
    const float* W = (const float*)d_in[1];   // [1152,10,16,8]
    float* out = (float*)d_out;               // [256,10,16]

    float* s_part = (float*)d_ws;                           // 32*256*160 f32
    float* Vsum   = s_part + (size_t)NSP * Bdim * CO;       // 256*160 f32
    _Float16* W16 = (_Float16*)(Vsum + Bdim * CO);          // 1280*1280 f16

    conv_w<<<dim3(1600), dim3(256), 0, stream>>>(W, W16);   // 409600/256

    const dim3 gi(NSP, Bdim / 16);   // (32, 16); quad fastest -> XCD affinity
    const dim3 bi(256);
    const dim3 gr((Bdim * CO) / 256);
    const dim3 br(256);

    // it 0
    caps_iter<true><<<gi, bi, 0, stream>>>(x, W16, Vsum, s_part);
    caps_reduce<0><<<gr, br, 0, stream>>>(s_part, Vsum, out);
    // it 1
    caps_iter<false><<<gi, bi, 0, stream>>>(x, W16, Vsum, s_part);
    caps_reduce<1><<<gr, br, 0, stream>>>(s_part, Vsum, out);
    // it 2 (final -> d_out)
    caps_iter<false><<<gi, bi, 0, stream>>>(x, W16, Vsum, s_part);
    caps_reduce<2><<<gr, br, 0, stream>>>(s_part, Vsum, out);
}